// Round 3
// baseline (449.401 us; speedup 1.0000x reference)
//
#include <hip/hip_runtime.h>

// Problem: B=16, C=1, H=2048, W=2048 fp32.
// out = a0*x + a1*(left+right) + a2*(up+down)   (replicate-padded 5-pt stencil)
//     + w0 + w1*x + w2*x^2 + w3*x^3             (Horner, CONST=0)
//
// v4 strategy (v3 post-mortem: 10-wide MLP on the window loads bought only
// ~8 us -> the limiter was the per-row neighbor exchange: 16 ds_bpermute
// (lgkmcnt waits in the compute stream) + 16 exec-mask divergent patch
// loads (dependent vmcnt waits per row)):
//  - Horizontal neighbors via UNCONDITIONAL scalar gathers with
//    cndmask-selected (clamped) addresses -- no branches, no shuffles,
//    no LDS, no exec-mask writes. Replicate edge comes from the address
//    clamp itself.
//  - ALL 26 loads (10 window dwordx4 + 16 neighbor dwords) issued upfront,
//    independent -> full MLP; compute loop is pure register VALU.
//  - XCD-aware bijective block swizzle (contiguous row-bands per XCD L2).
//  - Non-temporal stores (output never re-read).

#define H_DIM 2048
#define W_DIM 2048
#define W4    (W_DIM / 4)   // 512 float4 per row
#define RPT   8             // rows per thread
#define BLK   256           // threads per block -> 256 float4 cols = half row

typedef float fvec4 __attribute__((ext_vector_type(4)));

__global__ __launch_bounds__(BLK) void FCNN_63651415326860_kernel(
    const float* __restrict__ x,
    const float* __restrict__ a,
    const float* __restrict__ w,
    float* __restrict__ out)
{
    // ---- XCD-aware swizzle (bijective: gridDim.x = 8192, divisible by 8) ----
    const int chunk = gridDim.x >> 3;
    const int swz   = (blockIdx.x & 7) * chunk + (blockIdx.x >> 3);

    const int half = swz & 1;     // which half-row (0: cols 0..255, 1: 256..511)
    const int band = swz >> 1;    // 8-row band index across B*H

    const int col4 = half * BLK + (int)threadIdx.x;   // float4 column, 0..511

    const int rowg0 = band * RPT;              // first global row of this band
    const int row0  = rowg0 & (H_DIM - 1);     // row within image (RPT | H_DIM,
                                               // so a band never crosses images)

    const float4* __restrict__ x4 = (const float4*)x;
    const int v0 = rowg0 * W4 + col4;          // float4 index of row 0

    // clamped window-edge row addresses (block-uniform selects)
    const int vup = (row0 == 0)            ? v0                  : v0 - W4;
    const int vdn = (row0 + RPT == H_DIM)  ? v0 + (RPT - 1) * W4 : v0 + RPT * W4;

    // horizontal neighbor addresses: clamp via select, NO divergent branches.
    // col4==0      -> left neighbor is cur.x itself (replicate)
    // col4==W4-1   -> right neighbor is cur.w itself (replicate)
    const size_t s0    = (size_t)v0 * 4;
    const size_t offL  = (col4 != 0)      ? s0 - 1 : s0;        // x-offset row 0
    const size_t offR  = (col4 != W4 - 1) ? s0 + 4 : s0 + 3;

    // ---- issue ALL loads before any use: 26 independent VMEM ops ----
    float4 win[RPT + 2];                       // statically indexed after unroll
    float  lwv[RPT], rwv[RPT];
    #pragma unroll
    for (int r = 0; r < RPT; ++r)
        win[r + 1] = x4[v0 + r * W4];
    win[0]       = x4[vup];
    win[RPT + 1] = x4[vdn];
    #pragma unroll
    for (int r = 0; r < RPT; ++r) {
        lwv[r] = x[offL + (size_t)r * W_DIM];
        rwv[r] = x[offR + (size_t)r * W_DIM];
    }

    // broadcast scalars (uniform addresses -> s_load, cached)
    const float a0 = a[0], a1 = a[1], a2 = a[2];
    const float w0 = w[0], w1 = w[1], w2 = w[2], w3 = w[3];

    #pragma unroll
    for (int r = 0; r < RPT; ++r) {
        const float4 up  = win[r];
        const float4 cur = win[r + 1];
        const float4 dn  = win[r + 2];
        const float  lw  = lwv[r];
        const float  rw  = rwv[r];

        fvec4 res;
        res.x = a0 * cur.x + a1 * (lw    + cur.y) + a2 * (up.x + dn.x)
              + fmaf(fmaf(fmaf(w3, cur.x, w2), cur.x, w1), cur.x, w0);
        res.y = a0 * cur.y + a1 * (cur.x + cur.z) + a2 * (up.y + dn.y)
              + fmaf(fmaf(fmaf(w3, cur.y, w2), cur.y, w1), cur.y, w0);
        res.z = a0 * cur.z + a1 * (cur.y + cur.w) + a2 * (up.z + dn.z)
              + fmaf(fmaf(fmaf(w3, cur.z, w2), cur.z, w1), cur.z, w0);
        res.w = a0 * cur.w + a1 * (cur.z + rw   ) + a2 * (up.w + dn.w)
              + fmaf(fmaf(fmaf(w3, cur.w, w2), cur.w, w1), cur.w, w0);

        // output never re-read: bypass cache retention
        __builtin_nontemporal_store(res, (fvec4*)(out + (size_t)(v0 + r * W4) * 4));
    }
}

extern "C" void kernel_launch(void* const* d_in, const int* in_sizes, int n_in,
                              void* d_out, int out_size, void* d_ws, size_t ws_size,
                              hipStream_t stream) {
    const float* x = (const float*)d_in[0];   // 16*1*2048*2048 fp32
    const float* a = (const float*)d_in[1];   // 3 fp32
    const float* w = (const float*)d_in[2];   // 4 fp32
    float* out = (float*)d_out;

    const int total4 = out_size / 4;          // 16,777,216 float4s
    const int grid = total4 / (BLK * RPT);    // 8192 blocks

    FCNN_63651415326860_kernel<<<grid, BLK, 0, stream>>>(x, a, w, out);
}

// Round 4
// 436.091 us; speedup vs baseline: 1.0305x; 1.0305x over previous
//
#include <hip/hip_runtime.h>

// Problem: B=16, C=1, H=2048, W=2048 fp32.
// out = a0*x + a1*(left+right) + a2*(up+down)   (replicate-padded 5-pt stencil)
//     + w0 + w1*x + w2*x^2 + w3*x^3             (Horner, CONST=0)
//
// v5 = v4 with ONE variable changed: plain stores instead of
// __builtin_nontemporal_store. Rationale (v2-v4 post-mortem): occupancy,
// MLP, and shuffle-removal all nulled; the throughput wall is common to
// v2-v4 and absent in v1 (3.26 TB/s, plain stores) and in fillBuffer
// (6.6 TB/s, plain stores). Suspect: gfx950 'nt' store bit demotes the
// write stream (no L2 allocate / write-combine) and back-pressures the
// memory pipe when writes are ~half of total traffic.
//
// Kept from v4:
//  - 8 rows/thread, full 10-row window + 16 clamped scalar gathers issued
//    upfront (26 independent VMEM ops, branch-free, no LDS, no shuffles).
//  - XCD-aware bijective block swizzle (contiguous row-bands per XCD L2).

#define H_DIM 2048
#define W_DIM 2048
#define W4    (W_DIM / 4)   // 512 float4 per row
#define RPT   8             // rows per thread
#define BLK   256           // threads per block -> 256 float4 cols = half row

typedef float fvec4 __attribute__((ext_vector_type(4)));

__global__ __launch_bounds__(BLK) void FCNN_63651415326860_kernel(
    const float* __restrict__ x,
    const float* __restrict__ a,
    const float* __restrict__ w,
    float* __restrict__ out)
{
    // ---- XCD-aware swizzle (bijective: gridDim.x = 8192, divisible by 8) ----
    const int chunk = gridDim.x >> 3;
    const int swz   = (blockIdx.x & 7) * chunk + (blockIdx.x >> 3);

    const int half = swz & 1;     // which half-row (0: cols 0..255, 1: 256..511)
    const int band = swz >> 1;    // 8-row band index across B*H

    const int col4 = half * BLK + (int)threadIdx.x;   // float4 column, 0..511

    const int rowg0 = band * RPT;              // first global row of this band
    const int row0  = rowg0 & (H_DIM - 1);     // row within image (RPT | H_DIM,
                                               // so a band never crosses images)

    const float4* __restrict__ x4 = (const float4*)x;
    const int v0 = rowg0 * W4 + col4;          // float4 index of row 0

    // clamped window-edge row addresses (block-uniform selects)
    const int vup = (row0 == 0)            ? v0                  : v0 - W4;
    const int vdn = (row0 + RPT == H_DIM)  ? v0 + (RPT - 1) * W4 : v0 + RPT * W4;

    // horizontal neighbor addresses: clamp via select, NO divergent branches.
    const size_t s0    = (size_t)v0 * 4;
    const size_t offL  = (col4 != 0)      ? s0 - 1 : s0;
    const size_t offR  = (col4 != W4 - 1) ? s0 + 4 : s0 + 3;

    // ---- issue ALL loads before any use: 26 independent VMEM ops ----
    float4 win[RPT + 2];                       // statically indexed after unroll
    float  lwv[RPT], rwv[RPT];
    #pragma unroll
    for (int r = 0; r < RPT; ++r)
        win[r + 1] = x4[v0 + r * W4];
    win[0]       = x4[vup];
    win[RPT + 1] = x4[vdn];
    #pragma unroll
    for (int r = 0; r < RPT; ++r) {
        lwv[r] = x[offL + (size_t)r * W_DIM];
        rwv[r] = x[offR + (size_t)r * W_DIM];
    }

    // broadcast scalars (uniform addresses -> s_load, cached)
    const float a0 = a[0], a1 = a[1], a2 = a[2];
    const float w0 = w[0], w1 = w[1], w2 = w[2], w3 = w[3];

    #pragma unroll
    for (int r = 0; r < RPT; ++r) {
        const float4 up  = win[r];
        const float4 cur = win[r + 1];
        const float4 dn  = win[r + 2];
        const float  lw  = lwv[r];
        const float  rw  = rwv[r];

        fvec4 res;
        res.x = a0 * cur.x + a1 * (lw    + cur.y) + a2 * (up.x + dn.x)
              + fmaf(fmaf(fmaf(w3, cur.x, w2), cur.x, w1), cur.x, w0);
        res.y = a0 * cur.y + a1 * (cur.x + cur.z) + a2 * (up.y + dn.y)
              + fmaf(fmaf(fmaf(w3, cur.y, w2), cur.y, w1), cur.y, w0);
        res.z = a0 * cur.z + a1 * (cur.y + cur.w) + a2 * (up.z + dn.z)
              + fmaf(fmaf(fmaf(w3, cur.z, w2), cur.z, w1), cur.z, w0);
        res.w = a0 * cur.w + a1 * (cur.z + rw   ) + a2 * (up.w + dn.w)
              + fmaf(fmaf(fmaf(w3, cur.w, w2), cur.w, w1), cur.w, w0);

        // v5: PLAIN store (the single variable under test vs v4)
        *(fvec4*)(out + (size_t)(v0 + r * W4) * 4) = res;
    }
}

extern "C" void kernel_launch(void* const* d_in, const int* in_sizes, int n_in,
                              void* d_out, int out_size, void* d_ws, size_t ws_size,
                              hipStream_t stream) {
    const float* x = (const float*)d_in[0];   // 16*1*2048*2048 fp32
    const float* a = (const float*)d_in[1];   // 3 fp32
    const float* w = (const float*)d_in[2];   // 4 fp32
    float* out = (float*)d_out;

    const int total4 = out_size / 4;          // 16,777,216 float4s
    const int grid = total4 / (BLK * RPT);    // 8192 blocks

    FCNN_63651415326860_kernel<<<grid, BLK, 0, stream>>>(x, a, w, out);
}